// Round 18
// baseline (1143.441 us; speedup 1.0000x reference)
//
#include <hip/hip_runtime.h>
#include <math.h>

// Problem constants (from reference): B=128, S=2048, D=16, K=8
constexpr int Dc = 16;
constexpr int Kc = 8;
constexpr int Ntot = 128 * 2048 * 16;

// ---------------------------------------------------------------------------
// R18: drop the exact-comparator phase from k1 entirely.
// Error budget: accepted lanes (p >= 1e-3, converged Newton |F-z|<=1e-6) have
//   |x_np - x_true| <= 6e-8/p <= 6e-5   (np's own staircase quantization)
//   |x_mine - x_true| <= 1e-6/p <= 1e-3 (residual bound)
//   log-slope |p'|/p = max|u_k|/s_k <= ~40
//   => |(-logp)_mine - (-logp)_np| <= ~0.04 << bf16 ulp (0.0625 at [8,16))
// The bit-exact requirement lives ONLY in the flat class (p < 1e-3): those
// go to K2 rescue = EXACT R13 trajectory (bit-matching the passing kernel,
// which owns the 0.25 absmax). Newton derivative IS the mixture density:
// p = sum c_k * exp(-t^2), c_k = w_k/(s_k*sqrt(2pi)), t = (x-mu_k)*r_k --
// so the fast logdet is free at the final eval.
// ---------------------------------------------------------------------------
__device__ __forceinline__ float cr_expf(float x) { return (float)exp((double)x); }
__device__ __forceinline__ float cr_logf(float x) { return (float)log((double)x); }

__device__ __forceinline__ float erf_xla_f32(float x) {
    x = fminf(fmaxf(x, -4.0f), 4.0f);
    float y = __fmul_rn(x, x);
    float a = -2.72614225801306e-10f;
    a = __fadd_rn(__fmul_rn(a, y),  2.77068142495902e-08f);
    a = __fadd_rn(__fmul_rn(a, y), -2.10102402082508e-06f);
    a = __fadd_rn(__fmul_rn(a, y), -5.69250639462346e-05f);
    a = __fadd_rn(__fmul_rn(a, y), -7.34990630326855e-04f);
    a = __fadd_rn(__fmul_rn(a, y), -2.95459980854025e-03f);
    a = __fadd_rn(__fmul_rn(a, y), -1.60960333262415e-02f);
    float b = -1.45660718464996e-05f;
    b = __fadd_rn(__fmul_rn(b, y), -2.13374055278905e-04f);
    b = __fadd_rn(__fmul_rn(b, y), -1.68282697438203e-03f);
    b = __fadd_rn(__fmul_rn(b, y), -7.37332916720468e-03f);
    b = __fadd_rn(__fmul_rn(b, y), -1.42647390514189e-02f);
    return __fdiv_rn(__fmul_rn(x, a), b);
}

struct Params {
    float muk[Kc], sk[Kc], rk[Kc], wk[Kc];
    float lb, ub;
};

// Per-thread prep (rescue kernel) -- byte-identical values to R13.
__device__ __forceinline__ void prep_params(int d, const float* __restrict__ logits,
                                            const float* __restrict__ mu,
                                            const float* __restrict__ logstd, Params& P)
{
    const float SQRT2F = 1.41421356237309515f;
    float lg[Kc];
#pragma unroll
    for (int k = 0; k < Kc; ++k) lg[k] = logits[k];
    float lmax = lg[0];
#pragma unroll
    for (int k = 1; k < Kc; ++k) lmax = fmaxf(lmax, lg[k]);
    float ew[Kc];
#pragma unroll
    for (int k = 0; k < Kc; ++k) ew[k] = cr_expf(__fsub_rn(lg[k], lmax));
    float wsum = ew[0];
#pragma unroll
    for (int k = 1; k < Kc; ++k) wsum = __fadd_rn(wsum, ew[k]);
#pragma unroll
    for (int k = 0; k < Kc; ++k) P.wk[k] = __fdiv_rn(ew[k], wsum);

    float ssum = 0.f;
#pragma unroll
    for (int k = 0; k < Kc; ++k) {
        P.muk[k] = mu[k * Dc + d];
        P.sk[k]  = cr_expf(logstd[k * Dc + d]);
        P.rk[k]  = (float)(1.0 / ((double)P.sk[k] * (double)SQRT2F));
        ssum     = __fadd_rn(ssum, P.sk[k]);
    }
    float m10 = __fmul_rn(10.0f, ssum);
    float lb = __fsub_rn(P.muk[0], m10);
    float ub = __fadd_rn(P.muk[0], m10);
#pragma unroll
    for (int k = 1; k < Kc; ++k) {
        lb = fminf(lb, __fsub_rn(P.muk[k], m10));
        ub = fmaxf(ub, __fadd_rn(P.muk[k], m10));
    }
    P.lb = lb; P.ub = ub;
}

// Bit-identical to R13's comparator evaluation (value channel).
__device__ __forceinline__ float Feval(float x, const Params& P) {
    float acc = 0.f;
#pragma unroll
    for (int k = 0; k < Kc; ++k) {
        float t   = __fmul_rn(__fsub_rn(x, P.muk[k]), P.rk[k]);
        float e   = erf_xla_f32(t);
        float cdf = __fmul_rn(0.5f, __fadd_rn(1.0f, e));
        acc = __fadd_rn(acc, __fmul_rn(cdf, P.wk[k]));
    }
    return acc;
}

// Bit-identical to R13's log-det epilogue.
__device__ __forceinline__ float logdet_exact(float x, const Params& P) {
    const float INV_SQRT_2PIF = 0.39894228040143267f;
    float p = 0.f;
#pragma unroll
    for (int k = 0; k < Kc; ++k) {
        float u   = __fdiv_rn(__fsub_rn(x, P.muk[k]), P.sk[k]);
        float q   = __fmul_rn(__fmul_rn(-0.5f, u), u);
        float pdf = __fmul_rn(cr_expf(q), __fdiv_rn(INV_SQRT_2PIF, P.sk[k]));
        p = __fadd_rn(p, __fmul_rn(pdf, P.wk[k]));
    }
    return -cr_logf(p);
}

// R13's exact trajectory (value-space bisection, reference update rule).
__device__ __forceinline__ void traj_solve(float zv, const Params& P, float& xo, float& nldo) {
    float x = 0.f, lb = P.lb, ub = P.ub;
    int stable = 0;
    for (int it = 0; it < 200; ++it) {
        float acc = Feval(x, P);
        bool gt = acc > zv;
        float nx = __fmul_rn(__fadd_rn(x, gt ? lb : ub), 0.5f);
        if (gt) ub = x; else lb = x;
        stable = (nx == x) ? (stable + 1) : 0;
        x = nx;
        if (__all(stable >= 2)) break;
    }
    xo = x;
    nldo = logdet_exact(x, P);
}

__global__ __launch_bounds__(256)
void k1_newton(const float* __restrict__ z_in, const float* __restrict__ logits,
               const float* __restrict__ mu, const float* __restrict__ logstd,
               float* __restrict__ out_x, float* __restrict__ out_nld,
               unsigned int* __restrict__ ws_count, unsigned int* __restrict__ ws_list,
               unsigned int cap)
{
    const float SQRT2F = 1.41421356237309515f;
    const float INV_SQRT_2PIF = 0.39894228040143267f;
    __shared__ float s_ew[Kc], s_wk[Kc];
    __shared__ float s_mu[Kc][Dc], s_s[Kc][Dc], s_r[Kc][Dc], s_c[Kc][Dc];
    __shared__ float s_lb[Dc], s_ub[Dc];
    int tid = threadIdx.x;

    // ---- cooperative prep (CR transcendentals, once per block) ----
    if (tid < Kc) {
        float lmax = logits[0];
#pragma unroll
        for (int k = 1; k < Kc; ++k) lmax = fmaxf(lmax, logits[k]);
        s_ew[tid] = cr_expf(__fsub_rn(logits[tid], lmax));
    }
    if (tid < Kc * Dc) {
        int k = tid >> 4, d = tid & 15;
        s_mu[k][d] = mu[k * Dc + d];
        float s = cr_expf(logstd[k * Dc + d]);
        s_s[k][d] = s;
        s_r[k][d] = (float)(1.0 / ((double)s * (double)SQRT2F));
    }
    __syncthreads();
    if (tid < Kc) {
        float wsum = s_ew[0];
#pragma unroll
        for (int k = 1; k < Kc; ++k) wsum = __fadd_rn(wsum, s_ew[k]);
        s_wk[tid] = __fdiv_rn(s_ew[tid], wsum);
    }
    if (tid < Dc) {
        float ssum = 0.f;
#pragma unroll
        for (int k = 0; k < Kc; ++k) ssum = __fadd_rn(ssum, s_s[k][tid]);
        float m10 = __fmul_rn(10.0f, ssum);
        float lb = __fsub_rn(s_mu[0][tid], m10);
        float ub = __fadd_rn(s_mu[0][tid], m10);
#pragma unroll
        for (int k = 1; k < Kc; ++k) {
            lb = fminf(lb, __fsub_rn(s_mu[k][tid], m10));
            ub = fmaxf(ub, __fadd_rn(s_mu[k][tid], m10));
        }
        s_lb[tid] = lb; s_ub[tid] = ub;
    }
    __syncthreads();
    if (tid < Kc * Dc) {
        int k = tid >> 4, d = tid & 15;
        // c_k = w_k / (s_k * sqrt(2pi)) : density coefficient (= F' term)
        s_c[k][d] = s_wk[k] * INV_SQRT_2PIF / s_s[k][d];
    }
    __syncthreads();

    int i = blockIdx.x * blockDim.x + tid;   // Ntot % 256 == 0
    if (i >= Ntot) return;
    int d = i & (Dc - 1);
    float muk[Kc], rk[Kc], ck[Kc], wk[Kc];
#pragma unroll
    for (int k = 0; k < Kc; ++k) {
        muk[k] = s_mu[k][d]; rk[k] = s_r[k][d];
        ck[k]  = s_c[k][d];  wk[k] = s_wk[k];
    }
    float lb = s_lb[d], ub = s_ub[d];

    float zv = fminf(fmaxf(z_in[i], 0.f), 1.f);

    // ---- smooth safeguarded Newton: 9 evals (8 updates + final) ----
    float blo = lb, bhi = ub, x = 0.f;
    float acc = 0.f, den = 0.f;
#pragma unroll 1
    for (int it = 0; it < 9; ++it) {
        acc = 0.f; den = 0.f;
#pragma unroll
        for (int k = 0; k < Kc; ++k) {
            float t  = (x - muk[k]) * rk[k];
            float tc = fminf(fmaxf(t, -4.f), 4.f);
            float y  = tc * tc;
            float a = fmaf(-2.72614225801306e-10f, y,  2.77068142495902e-08f);
            a = fmaf(a, y, -2.10102402082508e-06f);
            a = fmaf(a, y, -5.69250639462346e-05f);
            a = fmaf(a, y, -7.34990630326855e-04f);
            a = fmaf(a, y, -2.95459980854025e-03f);
            a = fmaf(a, y, -1.60960333262415e-02f);
            float b = fmaf(-1.45660718464996e-05f, y, -2.13374055278905e-04f);
            b = fmaf(b, y, -1.68282697438203e-03f);
            b = fmaf(b, y, -7.37332916720468e-03f);
            b = fmaf(b, y, -1.42647390514189e-02f);
            float e = (tc * a) * __builtin_amdgcn_rcpf(b);
            acc = fmaf(0.5f * (1.f + e), wk[k], acc);
            den = fmaf(ck[k], __expf(-t * t), den);   // den == mixture density p
        }
        if (it == 8) break;                            // keep final acc/den at x
        bool gt = acc > zv;
        if (gt) bhi = x; else blo = x;
        float xn = x - (acc - zv) * __builtin_amdgcn_rcpf(den);
        if (!(xn > blo && xn < bhi)) xn = 0.5f * (blo + bhi);
        x = xn;
    }

    // ---- acceptance: decent density AND converged residual ----
    bool rescue = (den < 1e-3f) || (fabsf(acc - zv) > 1e-6f);

    float xout = 0.f, nldout = 0.f;
    if (!rescue) {
        xout   = x;
        nldout = -__logf(den);                         // fast logdet (err ~1e-6)
    } else {
        unsigned int idx = atomicAdd(ws_count, 1u);
        if (idx < cap) {
            ws_list[idx] = (unsigned int)i;
        } else {
            Params P;                                  // no scratch room: inline
            prep_params(d, logits, mu, logstd, P);
            traj_solve(zv, P, xout, nldout);
        }
    }
    out_x[i]   = xout;
    out_nld[i] = nldout;
}

__global__ __launch_bounds__(256)
void k2_rescue(const float* __restrict__ z_in, const float* __restrict__ logits,
               const float* __restrict__ mu, const float* __restrict__ logstd,
               float* __restrict__ out_x, float* __restrict__ out_nld,
               const unsigned int* __restrict__ ws_count,
               const unsigned int* __restrict__ ws_list, unsigned int cap)
{
    unsigned int n = *ws_count;
    if (n > cap) n = cap;
    for (unsigned int j = blockIdx.x * blockDim.x + threadIdx.x; j < n;
         j += gridDim.x * blockDim.x) {
        int i = (int)ws_list[j];
        Params P;
        prep_params(i & (Dc - 1), logits, mu, logstd, P);
        float zv = fminf(fmaxf(z_in[i], 0.f), 1.f);
        float x, nld;
        traj_solve(zv, P, x, nld);
        out_x[i]   = x;
        out_nld[i] = nld;
    }
}

extern "C" void kernel_launch(void* const* d_in, const int* in_sizes, int n_in,
                              void* d_out, int out_size, void* d_ws, size_t ws_size,
                              hipStream_t stream) {
    const float* z      = (const float*)d_in[0];
    const float* logits = (const float*)d_in[1];
    const float* mu     = (const float*)d_in[2];
    const float* logstd = (const float*)d_in[3];
    float* out_x   = (float*)d_out;
    float* out_nld = (float*)d_out + Ntot;

    unsigned int* ws_count = (unsigned int*)d_ws;
    unsigned int* ws_list  = (unsigned int*)((char*)d_ws + 16);
    size_t cap_sz = (ws_size > 16) ? (ws_size - 16) / 4 : 0;
    unsigned int cap = (unsigned int)((cap_sz > (size_t)Ntot) ? (size_t)Ntot : cap_sz);

    hipMemsetAsync(d_ws, 0, 16, stream);
    int threads = 256;
    int blocks  = (Ntot + threads - 1) / threads;
    k1_newton<<<blocks, threads, 0, stream>>>(z, logits, mu, logstd, out_x, out_nld,
                                              ws_count, ws_list, cap);
    k2_rescue<<<1024, threads, 0, stream>>>(z, logits, mu, logstd, out_x, out_nld,
                                            ws_count, ws_list, cap);
}

// Round 19
// 161.185 us; speedup vs baseline: 7.0940x; 7.0940x over previous
//
#include <hip/hip_runtime.h>
#include <math.h>

// Problem constants (from reference): B=128, S=2048, D=16, K=8
constexpr int Dc = 16;
constexpr int Kc = 8;
constexpr int Ntot = 128 * 2048 * 16;

// ---------------------------------------------------------------------------
// R19: fix R18's rescue flood. R18's counters: WRITE_SIZE +9MB => ~2.3M
// (55%) rescue entries; k1 VALUBusy 28% (list overflow -> inline 200-iter
// trajectories); k2 380us. Cause: 8 cold-start safeguarded-Newton iters
// can't reach |F-z|<=1e-6 from a +-20 bracket (safeguard = bisection of a
// 40-wide interval). R18 DID validate the fast path: 45% of elements took
// approximate outputs and absmax stayed 0.25 (budget: slope<=11, resid/p
// bound => d(-logp) <= 0.02 << bf16 ulp).
// Fix: (1) moment-matched Gaussian seed x0 = m_d + sig_d*sqrt2*erfinv(2z-1)
// (Giles f32 erfinv) -> Newton basin in 1 step, quadratic thereafter;
// (2) up to 14 iters, wave-uniform early exit on relative tolerance
// resid <= 1.5e-3*den (same validated budget); rescue = !done | den<1e-3
// -> K2 exact R13 trajectory (bit-matching), expected ~1-3% of elements.
// ---------------------------------------------------------------------------
__device__ __forceinline__ float cr_expf(float x) { return (float)exp((double)x); }
__device__ __forceinline__ float cr_logf(float x) { return (float)log((double)x); }

__device__ __forceinline__ float erf_xla_f32(float x) {
    x = fminf(fmaxf(x, -4.0f), 4.0f);
    float y = __fmul_rn(x, x);
    float a = -2.72614225801306e-10f;
    a = __fadd_rn(__fmul_rn(a, y),  2.77068142495902e-08f);
    a = __fadd_rn(__fmul_rn(a, y), -2.10102402082508e-06f);
    a = __fadd_rn(__fmul_rn(a, y), -5.69250639462346e-05f);
    a = __fadd_rn(__fmul_rn(a, y), -7.34990630326855e-04f);
    a = __fadd_rn(__fmul_rn(a, y), -2.95459980854025e-03f);
    a = __fadd_rn(__fmul_rn(a, y), -1.60960333262415e-02f);
    float b = -1.45660718464996e-05f;
    b = __fadd_rn(__fmul_rn(b, y), -2.13374055278905e-04f);
    b = __fadd_rn(__fmul_rn(b, y), -1.68282697438203e-03f);
    b = __fadd_rn(__fmul_rn(b, y), -7.37332916720468e-03f);
    b = __fadd_rn(__fmul_rn(b, y), -1.42647390514189e-02f);
    return __fdiv_rn(__fmul_rn(x, a), b);
}

// Giles (2012) single-precision erfinv.
__device__ __forceinline__ float erfinv_f32(float t) {
    float w = -__logf(fmaf(-t, t, 1.0f));
    float p;
    if (w < 5.0f) {
        w -= 2.5f;
        p = 2.81022636e-08f;
        p = fmaf(p, w, 3.43273939e-07f);
        p = fmaf(p, w, -3.5233877e-06f);
        p = fmaf(p, w, -4.39150654e-06f);
        p = fmaf(p, w, 2.1858087e-04f);
        p = fmaf(p, w, -1.25372503e-03f);
        p = fmaf(p, w, -4.17768164e-03f);
        p = fmaf(p, w, 2.46640727e-01f);
        p = fmaf(p, w, 1.50140941e+00f);
    } else {
        w = sqrtf(w) - 3.0f;
        p = -2.00214257e-04f;
        p = fmaf(p, w, 1.00950558e-04f);
        p = fmaf(p, w, 1.34934322e-03f);
        p = fmaf(p, w, -3.67342844e-03f);
        p = fmaf(p, w, 5.73950773e-03f);
        p = fmaf(p, w, -7.62246130e-03f);
        p = fmaf(p, w, 9.43887047e-03f);
        p = fmaf(p, w, 1.00167406e+00f);
        p = fmaf(p, w, 2.83297682e+00f);
    }
    return p * t;
}

struct Params {
    float muk[Kc], sk[Kc], rk[Kc], wk[Kc];
    float lb, ub;
};

// Per-thread prep (rescue kernel) -- byte-identical values to R13.
__device__ __forceinline__ void prep_params(int d, const float* __restrict__ logits,
                                            const float* __restrict__ mu,
                                            const float* __restrict__ logstd, Params& P)
{
    const float SQRT2F = 1.41421356237309515f;
    float lg[Kc];
#pragma unroll
    for (int k = 0; k < Kc; ++k) lg[k] = logits[k];
    float lmax = lg[0];
#pragma unroll
    for (int k = 1; k < Kc; ++k) lmax = fmaxf(lmax, lg[k]);
    float ew[Kc];
#pragma unroll
    for (int k = 0; k < Kc; ++k) ew[k] = cr_expf(__fsub_rn(lg[k], lmax));
    float wsum = ew[0];
#pragma unroll
    for (int k = 1; k < Kc; ++k) wsum = __fadd_rn(wsum, ew[k]);
#pragma unroll
    for (int k = 0; k < Kc; ++k) P.wk[k] = __fdiv_rn(ew[k], wsum);

    float ssum = 0.f;
#pragma unroll
    for (int k = 0; k < Kc; ++k) {
        P.muk[k] = mu[k * Dc + d];
        P.sk[k]  = cr_expf(logstd[k * Dc + d]);
        P.rk[k]  = (float)(1.0 / ((double)P.sk[k] * (double)SQRT2F));
        ssum     = __fadd_rn(ssum, P.sk[k]);
    }
    float m10 = __fmul_rn(10.0f, ssum);
    float lb = __fsub_rn(P.muk[0], m10);
    float ub = __fadd_rn(P.muk[0], m10);
#pragma unroll
    for (int k = 1; k < Kc; ++k) {
        lb = fminf(lb, __fsub_rn(P.muk[k], m10));
        ub = fmaxf(ub, __fadd_rn(P.muk[k], m10));
    }
    P.lb = lb; P.ub = ub;
}

// Bit-identical to R13's comparator evaluation (value channel).
__device__ __forceinline__ float Feval(float x, const Params& P) {
    float acc = 0.f;
#pragma unroll
    for (int k = 0; k < Kc; ++k) {
        float t   = __fmul_rn(__fsub_rn(x, P.muk[k]), P.rk[k]);
        float e   = erf_xla_f32(t);
        float cdf = __fmul_rn(0.5f, __fadd_rn(1.0f, e));
        acc = __fadd_rn(acc, __fmul_rn(cdf, P.wk[k]));
    }
    return acc;
}

// Bit-identical to R13's log-det epilogue.
__device__ __forceinline__ float logdet_exact(float x, const Params& P) {
    const float INV_SQRT_2PIF = 0.39894228040143267f;
    float p = 0.f;
#pragma unroll
    for (int k = 0; k < Kc; ++k) {
        float u   = __fdiv_rn(__fsub_rn(x, P.muk[k]), P.sk[k]);
        float q   = __fmul_rn(__fmul_rn(-0.5f, u), u);
        float pdf = __fmul_rn(cr_expf(q), __fdiv_rn(INV_SQRT_2PIF, P.sk[k]));
        p = __fadd_rn(p, __fmul_rn(pdf, P.wk[k]));
    }
    return -cr_logf(p);
}

// R13's exact trajectory (value-space bisection, reference update rule).
__device__ __forceinline__ void traj_solve(float zv, const Params& P, float& xo, float& nldo) {
    float x = 0.f, lb = P.lb, ub = P.ub;
    int stable = 0;
    for (int it = 0; it < 200; ++it) {
        float acc = Feval(x, P);
        bool gt = acc > zv;
        float nx = __fmul_rn(__fadd_rn(x, gt ? lb : ub), 0.5f);
        if (gt) ub = x; else lb = x;
        stable = (nx == x) ? (stable + 1) : 0;
        x = nx;
        if (__all(stable >= 2)) break;
    }
    xo = x;
    nldo = logdet_exact(x, P);
}

__global__ __launch_bounds__(256)
void k1_newton(const float* __restrict__ z_in, const float* __restrict__ logits,
               const float* __restrict__ mu, const float* __restrict__ logstd,
               float* __restrict__ out_x, float* __restrict__ out_nld,
               unsigned int* __restrict__ ws_count, unsigned int* __restrict__ ws_list,
               unsigned int cap)
{
    const float SQRT2F = 1.41421356237309515f;
    const float INV_SQRT_2PIF = 0.39894228040143267f;
    __shared__ float s_ew[Kc], s_wk[Kc];
    __shared__ float s_mu[Kc][Dc], s_s[Kc][Dc], s_r[Kc][Dc], s_c[Kc][Dc];
    __shared__ float s_lb[Dc], s_ub[Dc], s_m[Dc], s_sig[Dc];
    int tid = threadIdx.x;

    // ---- cooperative prep (CR transcendentals, once per block) ----
    if (tid < Kc) {
        float lmax = logits[0];
#pragma unroll
        for (int k = 1; k < Kc; ++k) lmax = fmaxf(lmax, logits[k]);
        s_ew[tid] = cr_expf(__fsub_rn(logits[tid], lmax));
    }
    if (tid < Kc * Dc) {
        int k = tid >> 4, d = tid & 15;
        s_mu[k][d] = mu[k * Dc + d];
        float s = cr_expf(logstd[k * Dc + d]);
        s_s[k][d] = s;
        s_r[k][d] = (float)(1.0 / ((double)s * (double)SQRT2F));
    }
    __syncthreads();
    if (tid < Kc) {
        float wsum = s_ew[0];
#pragma unroll
        for (int k = 1; k < Kc; ++k) wsum = __fadd_rn(wsum, s_ew[k]);
        s_wk[tid] = __fdiv_rn(s_ew[tid], wsum);
    }
    __syncthreads();
    if (tid < Dc) {
        float ssum = 0.f, m = 0.f;
#pragma unroll
        for (int k = 0; k < Kc; ++k) {
            ssum = __fadd_rn(ssum, s_s[k][tid]);
            m    = fmaf(s_wk[k], s_mu[k][tid], m);
        }
        float var = 0.f;
#pragma unroll
        for (int k = 0; k < Kc; ++k) {
            float dm = s_mu[k][tid] - m;
            var = fmaf(s_wk[k], fmaf(dm, dm, s_s[k][tid] * s_s[k][tid]), var);
        }
        s_m[tid]   = m;
        s_sig[tid] = sqrtf(var);
        float m10 = __fmul_rn(10.0f, ssum);
        float lb = __fsub_rn(s_mu[0][tid], m10);
        float ub = __fadd_rn(s_mu[0][tid], m10);
#pragma unroll
        for (int k = 1; k < Kc; ++k) {
            lb = fminf(lb, __fsub_rn(s_mu[k][tid], m10));
            ub = fmaxf(ub, __fadd_rn(s_mu[k][tid], m10));
        }
        s_lb[tid] = lb; s_ub[tid] = ub;
    }
    if (tid < Kc * Dc) {
        int k = tid >> 4, d = tid & 15;
        // c_k = w_k / (s_k*sqrt(2pi)) : density coefficient (F' term).
        // s_wk written by lanes 0-7 before this point only if syncthreads --
        // we synced above after s_wk store.
        s_c[k][d] = s_wk[k] * INV_SQRT_2PIF / s_s[k][d];
    }
    __syncthreads();

    int i = blockIdx.x * blockDim.x + tid;   // Ntot % 256 == 0
    if (i >= Ntot) return;
    int d = i & (Dc - 1);
    float muk[Kc], rk[Kc], ck[Kc], wk[Kc];
#pragma unroll
    for (int k = 0; k < Kc; ++k) {
        muk[k] = s_mu[k][d]; rk[k] = s_r[k][d];
        ck[k]  = s_c[k][d];  wk[k] = s_wk[k];
    }
    float lb = s_lb[d], ub = s_ub[d];

    float zv = fminf(fmaxf(z_in[i], 0.f), 1.f);

    // ---- moment-matched Gaussian seed ----
    float tt = fminf(fmaxf(2.f * zv - 1.f, -0.999999f), 0.999999f);
    float x  = fmaf(s_sig[d] * SQRT2F, erfinv_f32(tt), s_m[d]);
    x = fminf(fmaxf(x, lb + 1e-3f), ub - 1e-3f);

    // ---- safeguarded Newton to relative tolerance, wave-uniform exit ----
    float blo = lb, bhi = ub;
    float acc = 0.f, den = 0.f;
    bool done = false;
#pragma unroll 1
    for (int it = 0; it < 14; ++it) {
        acc = 0.f; den = 0.f;
#pragma unroll
        for (int k = 0; k < Kc; ++k) {
            float t  = (x - muk[k]) * rk[k];
            float tc = fminf(fmaxf(t, -4.f), 4.f);
            float y  = tc * tc;
            float a = fmaf(-2.72614225801306e-10f, y,  2.77068142495902e-08f);
            a = fmaf(a, y, -2.10102402082508e-06f);
            a = fmaf(a, y, -5.69250654462346e-05f);
            a = fmaf(a, y, -7.34990630326855e-04f);
            a = fmaf(a, y, -2.95459980854025e-03f);
            a = fmaf(a, y, -1.60960333262415e-02f);
            float b = fmaf(-1.45660718464996e-05f, y, -2.13374055278905e-04f);
            b = fmaf(b, y, -1.68282697438203e-03f);
            b = fmaf(b, y, -7.37332916720468e-03f);
            b = fmaf(b, y, -1.42647390514189e-02f);
            float e = (tc * a) * __builtin_amdgcn_rcpf(b);
            acc = fmaf(0.5f * (1.f + e), wk[k], acc);
            den = fmaf(ck[k], __expf(-t * t), den);   // den == mixture density p
        }
        // relative tolerance: d(-logp) <= slope(<=11) * resid/den <= 0.017
        done = done || (fabsf(acc - zv) <= 1.5e-3f * den);
        if (__all(done)) break;
        if (!done) {
            bool gt = acc > zv;
            if (gt) bhi = x; else blo = x;
            float xn = x - (acc - zv) * __builtin_amdgcn_rcpf(den);
            if (!(xn > blo && xn < bhi)) xn = 0.5f * (blo + bhi);
            x = xn;
        }
    }

    // ---- acceptance: converged AND decent density ----
    bool rescue = (!done) || (den < 1e-3f);

    float xout = 0.f, nldout = 0.f;
    if (!rescue) {
        xout   = x;
        nldout = -__logf(den);                         // fast logdet (err ~1e-6)
    } else {
        unsigned int idx = atomicAdd(ws_count, 1u);
        if (idx < cap) {
            ws_list[idx] = (unsigned int)i;
        } else {
            Params P;                                  // no scratch room: inline
            prep_params(d, logits, mu, logstd, P);
            traj_solve(zv, P, xout, nldout);
        }
    }
    out_x[i]   = xout;
    out_nld[i] = nldout;
}

__global__ __launch_bounds__(256)
void k2_rescue(const float* __restrict__ z_in, const float* __restrict__ logits,
               const float* __restrict__ mu, const float* __restrict__ logstd,
               float* __restrict__ out_x, float* __restrict__ out_nld,
               const unsigned int* __restrict__ ws_count,
               const unsigned int* __restrict__ ws_list, unsigned int cap)
{
    unsigned int n = *ws_count;
    if (n > cap) n = cap;
    for (unsigned int j = blockIdx.x * blockDim.x + threadIdx.x; j < n;
         j += gridDim.x * blockDim.x) {
        int i = (int)ws_list[j];
        Params P;
        prep_params(i & (Dc - 1), logits, mu, logstd, P);
        float zv = fminf(fmaxf(z_in[i], 0.f), 1.f);
        float x, nld;
        traj_solve(zv, P, x, nld);
        out_x[i]   = x;
        out_nld[i] = nld;
    }
}

extern "C" void kernel_launch(void* const* d_in, const int* in_sizes, int n_in,
                              void* d_out, int out_size, void* d_ws, size_t ws_size,
                              hipStream_t stream) {
    const float* z      = (const float*)d_in[0];
    const float* logits = (const float*)d_in[1];
    const float* mu     = (const float*)d_in[2];
    const float* logstd = (const float*)d_in[3];
    float* out_x   = (float*)d_out;
    float* out_nld = (float*)d_out + Ntot;

    unsigned int* ws_count = (unsigned int*)d_ws;
    unsigned int* ws_list  = (unsigned int*)((char*)d_ws + 16);
    size_t cap_sz = (ws_size > 16) ? (ws_size - 16) / 4 : 0;
    unsigned int cap = (unsigned int)((cap_sz > (size_t)Ntot) ? (size_t)Ntot : cap_sz);

    hipMemsetAsync(d_ws, 0, 16, stream);
    int threads = 256;
    int blocks  = (Ntot + threads - 1) / threads;
    k1_newton<<<blocks, threads, 0, stream>>>(z, logits, mu, logstd, out_x, out_nld,
                                              ws_count, ws_list, cap);
    k2_rescue<<<1024, threads, 0, stream>>>(z, logits, mu, logstd, out_x, out_nld,
                                            ws_count, ws_list, cap);
}

// Round 20
// 123.380 us; speedup vs baseline: 9.2677x; 1.3064x over previous
//
#include <hip/hip_runtime.h>
#include <math.h>

// Problem constants (from reference): B=128, S=2048, D=16, K=8
constexpr int Dc = 16;
constexpr int Kc = 8;
constexpr int Ntot = 128 * 2048 * 16;

// ---------------------------------------------------------------------------
// R20: cut the wave-max iteration drag. R19's k1 = 156us = ~2900 lane-cyc/el
// = ~13 iters/wave: relative tolerance (resid<=1.5e-3*den) is slow/unreachable
// for den in [1e-3,1e-2] lanes and never-converging lanes drag whole waves to
// the 14-iter cap. Fixes:
//  1. Iter cap 8: unconverged -> rescue (exact R13 trajectory in K2, the
//     bit-exact path that owns absmax 0.25). Rescue only GROWS -> absmax safe.
//  2. Halley correction (F'' = -2 sum g*t*r reuses g=c*exp(-t^2); denom
//     clamped [0.5,2]x Newton): cubic convergence, 1-2 fewer iters.
//  3. acc folds 0.5 into weights (starts at 0.5, fmaf(wh,e)): -8 mul/iter.
// Acceptance unchanged: resid<=1.5e-3*den AND den>=1e-3 => d(-logp)<=0.018
// << bf16 ulp (validated at scale by R18/R19).
// ---------------------------------------------------------------------------
__device__ __forceinline__ float cr_expf(float x) { return (float)exp((double)x); }
__device__ __forceinline__ float cr_logf(float x) { return (float)log((double)x); }

__device__ __forceinline__ float erf_xla_f32(float x) {
    x = fminf(fmaxf(x, -4.0f), 4.0f);
    float y = __fmul_rn(x, x);
    float a = -2.72614225801306e-10f;
    a = __fadd_rn(__fmul_rn(a, y),  2.77068142495902e-08f);
    a = __fadd_rn(__fmul_rn(a, y), -2.10102402082508e-06f);
    a = __fadd_rn(__fmul_rn(a, y), -5.69250639462346e-05f);
    a = __fadd_rn(__fmul_rn(a, y), -7.34990630326855e-04f);
    a = __fadd_rn(__fmul_rn(a, y), -2.95459980854025e-03f);
    a = __fadd_rn(__fmul_rn(a, y), -1.60960333262415e-02f);
    float b = -1.45660718464996e-05f;
    b = __fadd_rn(__fmul_rn(b, y), -2.13374055278905e-04f);
    b = __fadd_rn(__fmul_rn(b, y), -1.68282697438203e-03f);
    b = __fadd_rn(__fmul_rn(b, y), -7.37332916720468e-03f);
    b = __fadd_rn(__fmul_rn(b, y), -1.42647390514189e-02f);
    return __fdiv_rn(__fmul_rn(x, a), b);
}

// Giles (2012) single-precision erfinv.
__device__ __forceinline__ float erfinv_f32(float t) {
    float w = -__logf(fmaf(-t, t, 1.0f));
    float p;
    if (w < 5.0f) {
        w -= 2.5f;
        p = 2.81022636e-08f;
        p = fmaf(p, w, 3.43273939e-07f);
        p = fmaf(p, w, -3.5233877e-06f);
        p = fmaf(p, w, -4.39150654e-06f);
        p = fmaf(p, w, 2.1858087e-04f);
        p = fmaf(p, w, -1.25372503e-03f);
        p = fmaf(p, w, -4.17768164e-03f);
        p = fmaf(p, w, 2.46640727e-01f);
        p = fmaf(p, w, 1.50140941e+00f);
    } else {
        w = sqrtf(w) - 3.0f;
        p = -2.00214257e-04f;
        p = fmaf(p, w, 1.00950558e-04f);
        p = fmaf(p, w, 1.34934322e-03f);
        p = fmaf(p, w, -3.67342844e-03f);
        p = fmaf(p, w, 5.73950773e-03f);
        p = fmaf(p, w, -7.62246130e-03f);
        p = fmaf(p, w, 9.43887047e-03f);
        p = fmaf(p, w, 1.00167406e+00f);
        p = fmaf(p, w, 2.83297682e+00f);
    }
    return p * t;
}

struct Params {
    float muk[Kc], sk[Kc], rk[Kc], wk[Kc];
    float lb, ub;
};

// Per-thread prep (rescue kernel) -- byte-identical values to R13.
__device__ __forceinline__ void prep_params(int d, const float* __restrict__ logits,
                                            const float* __restrict__ mu,
                                            const float* __restrict__ logstd, Params& P)
{
    const float SQRT2F = 1.41421356237309515f;
    float lg[Kc];
#pragma unroll
    for (int k = 0; k < Kc; ++k) lg[k] = logits[k];
    float lmax = lg[0];
#pragma unroll
    for (int k = 1; k < Kc; ++k) lmax = fmaxf(lmax, lg[k]);
    float ew[Kc];
#pragma unroll
    for (int k = 0; k < Kc; ++k) ew[k] = cr_expf(__fsub_rn(lg[k], lmax));
    float wsum = ew[0];
#pragma unroll
    for (int k = 1; k < Kc; ++k) wsum = __fadd_rn(wsum, ew[k]);
#pragma unroll
    for (int k = 0; k < Kc; ++k) P.wk[k] = __fdiv_rn(ew[k], wsum);

    float ssum = 0.f;
#pragma unroll
    for (int k = 0; k < Kc; ++k) {
        P.muk[k] = mu[k * Dc + d];
        P.sk[k]  = cr_expf(logstd[k * Dc + d]);
        P.rk[k]  = (float)(1.0 / ((double)P.sk[k] * (double)SQRT2F));
        ssum     = __fadd_rn(ssum, P.sk[k]);
    }
    float m10 = __fmul_rn(10.0f, ssum);
    float lb = __fsub_rn(P.muk[0], m10);
    float ub = __fadd_rn(P.muk[0], m10);
#pragma unroll
    for (int k = 1; k < Kc; ++k) {
        lb = fminf(lb, __fsub_rn(P.muk[k], m10));
        ub = fmaxf(ub, __fadd_rn(P.muk[k], m10));
    }
    P.lb = lb; P.ub = ub;
}

// Bit-identical to R13's comparator evaluation (value channel).
__device__ __forceinline__ float Feval(float x, const Params& P) {
    float acc = 0.f;
#pragma unroll
    for (int k = 0; k < Kc; ++k) {
        float t   = __fmul_rn(__fsub_rn(x, P.muk[k]), P.rk[k]);
        float e   = erf_xla_f32(t);
        float cdf = __fmul_rn(0.5f, __fadd_rn(1.0f, e));
        acc = __fadd_rn(acc, __fmul_rn(cdf, P.wk[k]));
    }
    return acc;
}

// Bit-identical to R13's log-det epilogue.
__device__ __forceinline__ float logdet_exact(float x, const Params& P) {
    const float INV_SQRT_2PIF = 0.39894228040143267f;
    float p = 0.f;
#pragma unroll
    for (int k = 0; k < Kc; ++k) {
        float u   = __fdiv_rn(__fsub_rn(x, P.muk[k]), P.sk[k]);
        float q   = __fmul_rn(__fmul_rn(-0.5f, u), u);
        float pdf = __fmul_rn(cr_expf(q), __fdiv_rn(INV_SQRT_2PIF, P.sk[k]));
        p = __fadd_rn(p, __fmul_rn(pdf, P.wk[k]));
    }
    return -cr_logf(p);
}

// R13's exact trajectory (value-space bisection, reference update rule).
__device__ __forceinline__ void traj_solve(float zv, const Params& P, float& xo, float& nldo) {
    float x = 0.f, lb = P.lb, ub = P.ub;
    int stable = 0;
    for (int it = 0; it < 200; ++it) {
        float acc = Feval(x, P);
        bool gt = acc > zv;
        float nx = __fmul_rn(__fadd_rn(x, gt ? lb : ub), 0.5f);
        if (gt) ub = x; else lb = x;
        stable = (nx == x) ? (stable + 1) : 0;
        x = nx;
        if (__all(stable >= 2)) break;
    }
    xo = x;
    nldo = logdet_exact(x, P);
}

__global__ __launch_bounds__(256)
void k1_newton(const float* __restrict__ z_in, const float* __restrict__ logits,
               const float* __restrict__ mu, const float* __restrict__ logstd,
               float* __restrict__ out_x, float* __restrict__ out_nld,
               unsigned int* __restrict__ ws_count, unsigned int* __restrict__ ws_list,
               unsigned int cap)
{
    const float SQRT2F = 1.41421356237309515f;
    const float INV_SQRT_2PIF = 0.39894228040143267f;
    __shared__ float s_ew[Kc], s_wk[Kc];
    __shared__ float s_mu[Kc][Dc], s_s[Kc][Dc], s_r[Kc][Dc], s_c[Kc][Dc];
    __shared__ float s_lb[Dc], s_ub[Dc], s_m[Dc], s_sig[Dc];
    int tid = threadIdx.x;

    // ---- cooperative prep (CR transcendentals, once per block) ----
    if (tid < Kc) {
        float lmax = logits[0];
#pragma unroll
        for (int k = 1; k < Kc; ++k) lmax = fmaxf(lmax, logits[k]);
        s_ew[tid] = cr_expf(__fsub_rn(logits[tid], lmax));
    }
    if (tid < Kc * Dc) {
        int k = tid >> 4, d = tid & 15;
        s_mu[k][d] = mu[k * Dc + d];
        float s = cr_expf(logstd[k * Dc + d]);
        s_s[k][d] = s;
        s_r[k][d] = (float)(1.0 / ((double)s * (double)SQRT2F));
    }
    __syncthreads();
    if (tid < Kc) {
        float wsum = s_ew[0];
#pragma unroll
        for (int k = 1; k < Kc; ++k) wsum = __fadd_rn(wsum, s_ew[k]);
        s_wk[tid] = __fdiv_rn(s_ew[tid], wsum);
    }
    __syncthreads();
    if (tid < Dc) {
        float ssum = 0.f, m = 0.f;
#pragma unroll
        for (int k = 0; k < Kc; ++k) {
            ssum = __fadd_rn(ssum, s_s[k][tid]);
            m    = fmaf(s_wk[k], s_mu[k][tid], m);
        }
        float var = 0.f;
#pragma unroll
        for (int k = 0; k < Kc; ++k) {
            float dm = s_mu[k][tid] - m;
            var = fmaf(s_wk[k], fmaf(dm, dm, s_s[k][tid] * s_s[k][tid]), var);
        }
        s_m[tid]   = m;
        s_sig[tid] = sqrtf(var);
        float m10 = __fmul_rn(10.0f, ssum);
        float lb = __fsub_rn(s_mu[0][tid], m10);
        float ub = __fadd_rn(s_mu[0][tid], m10);
#pragma unroll
        for (int k = 1; k < Kc; ++k) {
            lb = fminf(lb, __fsub_rn(s_mu[k][tid], m10));
            ub = fmaxf(ub, __fadd_rn(s_mu[k][tid], m10));
        }
        s_lb[tid] = lb; s_ub[tid] = ub;
    }
    if (tid < Kc * Dc) {
        int k = tid >> 4, d = tid & 15;
        s_c[k][d] = s_wk[k] * INV_SQRT_2PIF / s_s[k][d];  // density coeff
    }
    __syncthreads();

    int i = blockIdx.x * blockDim.x + tid;   // Ntot % 256 == 0
    if (i >= Ntot) return;
    int d = i & (Dc - 1);
    float muk[Kc], rk[Kc], ck[Kc], wh[Kc];
#pragma unroll
    for (int k = 0; k < Kc; ++k) {
        muk[k] = s_mu[k][d]; rk[k] = s_r[k][d];
        ck[k]  = s_c[k][d];  wh[k] = 0.5f * s_wk[k];
    }
    float lb = s_lb[d], ub = s_ub[d];

    float zv = fminf(fmaxf(z_in[i], 0.f), 1.f);

    // ---- moment-matched Gaussian seed ----
    float tt = fminf(fmaxf(2.f * zv - 1.f, -0.999999f), 0.999999f);
    float x  = fmaf(s_sig[d] * SQRT2F, erfinv_f32(tt), s_m[d]);
    x = fminf(fmaxf(x, lb + 1e-3f), ub - 1e-3f);

    // ---- safeguarded Halley-Newton, cap 8, wave-uniform early exit ----
    float blo = lb, bhi = ub;
    float acc = 0.f, den = 0.f;
    bool done = false;
#pragma unroll 1
    for (int it = 0; it < 8; ++it) {
        acc = 0.5f; den = 0.f;
        float f2 = 0.f;                       // accumulates sum g*t*r (for F'')
#pragma unroll
        for (int k = 0; k < Kc; ++k) {
            float t  = (x - muk[k]) * rk[k];
            float tc = fminf(fmaxf(t, -4.f), 4.f);
            float y  = tc * tc;
            float a = fmaf(-2.72614225801306e-10f, y,  2.77068142495902e-08f);
            a = fmaf(a, y, -2.10102402082508e-06f);
            a = fmaf(a, y, -5.69250639462346e-05f);
            a = fmaf(a, y, -7.34990630326855e-04f);
            a = fmaf(a, y, -2.95459980854025e-03f);
            a = fmaf(a, y, -1.60960333262415e-02f);
            float b = fmaf(-1.45660718464996e-05f, y, -2.13374055278905e-04f);
            b = fmaf(b, y, -1.68282697438203e-03f);
            b = fmaf(b, y, -7.37332916720468e-03f);
            b = fmaf(b, y, -1.42647390514189e-02f);
            float e = (tc * a) * __builtin_amdgcn_rcpf(b);
            acc = fmaf(wh[k], e, acc);                 // F = 0.5 + sum wh*e
            float g = ck[k] * __expf(-t * t);          // density component
            den = den + g;
            f2  = fmaf(g, t * rk[k], f2);              // for F'' = -2*f2
        }
        float r = acc - zv;
        done = done || (fabsf(r) <= 1.5e-3f * den);
        if (__all(done)) break;
        if (!done) {
            bool gt = r > 0.f;
            if (gt) bhi = x; else blo = x;
            float invd = __builtin_amdgcn_rcpf(den);
            float nstep = r * invd;                    // Newton step
            // Halley: step = nstep / (1 - r*F''/(2 F'^2)); F'' = -2*f2
            float hden = fmaf(nstep * invd, f2, 1.0f); // 1 + r*f2/den^2
            hden = fminf(fmaxf(hden, 0.5f), 2.0f);
            float xn = x - nstep * __builtin_amdgcn_rcpf(hden);
            if (!(xn > blo && xn < bhi)) xn = 0.5f * (blo + bhi);
            x = xn;
        }
    }

    // ---- acceptance: converged AND decent density ----
    bool rescue = (!done) || (den < 1e-3f);

    float xout = 0.f, nldout = 0.f;
    if (!rescue) {
        xout   = x;
        nldout = -__logf(den);                         // fast logdet (err ~1e-6)
    } else {
        unsigned int idx = atomicAdd(ws_count, 1u);
        if (idx < cap) {
            ws_list[idx] = (unsigned int)i;
        } else {
            Params P;                                  // no scratch room: inline
            prep_params(d, logits, mu, logstd, P);
            traj_solve(zv, P, xout, nldout);
        }
    }
    out_x[i]   = xout;
    out_nld[i] = nldout;
}

__global__ __launch_bounds__(256)
void k2_rescue(const float* __restrict__ z_in, const float* __restrict__ logits,
               const float* __restrict__ mu, const float* __restrict__ logstd,
               float* __restrict__ out_x, float* __restrict__ out_nld,
               const unsigned int* __restrict__ ws_count,
               const unsigned int* __restrict__ ws_list, unsigned int cap)
{
    unsigned int n = *ws_count;
    if (n > cap) n = cap;
    for (unsigned int j = blockIdx.x * blockDim.x + threadIdx.x; j < n;
         j += gridDim.x * blockDim.x) {
        int i = (int)ws_list[j];
        Params P;
        prep_params(i & (Dc - 1), logits, mu, logstd, P);
        float zv = fminf(fmaxf(z_in[i], 0.f), 1.f);
        float x, nld;
        traj_solve(zv, P, x, nld);
        out_x[i]   = x;
        out_nld[i] = nld;
    }
}

extern "C" void kernel_launch(void* const* d_in, const int* in_sizes, int n_in,
                              void* d_out, int out_size, void* d_ws, size_t ws_size,
                              hipStream_t stream) {
    const float* z      = (const float*)d_in[0];
    const float* logits = (const float*)d_in[1];
    const float* mu     = (const float*)d_in[2];
    const float* logstd = (const float*)d_in[3];
    float* out_x   = (float*)d_out;
    float* out_nld = (float*)d_out + Ntot;

    unsigned int* ws_count = (unsigned int*)d_ws;
    unsigned int* ws_list  = (unsigned int*)((char*)d_ws + 16);
    size_t cap_sz = (ws_size > 16) ? (ws_size - 16) / 4 : 0;
    unsigned int cap = (unsigned int)((cap_sz > (size_t)Ntot) ? (size_t)Ntot : cap_sz);

    hipMemsetAsync(d_ws, 0, 16, stream);
    int threads = 256;
    int blocks  = (Ntot + threads - 1) / threads;
    k1_newton<<<blocks, threads, 0, stream>>>(z, logits, mu, logstd, out_x, out_nld,
                                              ws_count, ws_list, cap);
    k2_rescue<<<1024, threads, 0, stream>>>(z, logits, mu, logstd, out_x, out_nld,
                                            ws_count, ws_list, cap);
}

// Round 21
// 114.271 us; speedup vs baseline: 10.0064x; 1.0797x over previous
//
#include <hip/hip_runtime.h>
#include <math.h>

// Problem constants (from reference): B=128, S=2048, D=16, K=8
constexpr int Dc = 16;
constexpr int Kc = 8;
constexpr int Ntot = 128 * 2048 * 16;

// ---------------------------------------------------------------------------
// R21: strip stragglers from the wave-exit condition. R20's k1 (112us,
// ~2100 lane-cyc/el) is wave-max-bound: ~1% never-converging (flat) lanes
// are randomly scattered, so ~half the waves contain one and grind to the
// 8-iter cap while healthy lanes idle (typical Halley convergence is 3-4).
// Fix: lanes with den < 1e-3 after >=1 grace iteration are destined for
// rescue -> mark 'flat', exclude from the exit condition
// (__all(conv || flat)), stop updating them. Acceptance unchanged:
// rescue = !conv || den<1e-3 at exit; flat lanes take the bit-exact R13
// trajectory in K2 exactly as before (rescue set can only grow -> absmax
// safe; outputs move toward the bit-exact path).
// ---------------------------------------------------------------------------
__device__ __forceinline__ float cr_expf(float x) { return (float)exp((double)x); }
__device__ __forceinline__ float cr_logf(float x) { return (float)log((double)x); }

__device__ __forceinline__ float erf_xla_f32(float x) {
    x = fminf(fmaxf(x, -4.0f), 4.0f);
    float y = __fmul_rn(x, x);
    float a = -2.72614225801306e-10f;
    a = __fadd_rn(__fmul_rn(a, y),  2.77068142495902e-08f);
    a = __fadd_rn(__fmul_rn(a, y), -2.10102402082508e-06f);
    a = __fadd_rn(__fmul_rn(a, y), -5.69250639462346e-05f);
    a = __fadd_rn(__fmul_rn(a, y), -7.34990630326855e-04f);
    a = __fadd_rn(__fmul_rn(a, y), -2.95459980854025e-03f);
    a = __fadd_rn(__fmul_rn(a, y), -1.60960333262415e-02f);
    float b = -1.45660718464996e-05f;
    b = __fadd_rn(__fmul_rn(b, y), -2.13374055278905e-04f);
    b = __fadd_rn(__fmul_rn(b, y), -1.68282697438203e-03f);
    b = __fadd_rn(__fmul_rn(b, y), -7.37332916720468e-03f);
    b = __fadd_rn(__fmul_rn(b, y), -1.42647390514189e-02f);
    return __fdiv_rn(__fmul_rn(x, a), b);
}

// Giles (2012) single-precision erfinv.
__device__ __forceinline__ float erfinv_f32(float t) {
    float w = -__logf(fmaf(-t, t, 1.0f));
    float p;
    if (w < 5.0f) {
        w -= 2.5f;
        p = 2.81022636e-08f;
        p = fmaf(p, w, 3.43273939e-07f);
        p = fmaf(p, w, -3.5233877e-06f);
        p = fmaf(p, w, -4.39150654e-06f);
        p = fmaf(p, w, 2.1858087e-04f);
        p = fmaf(p, w, -1.25372503e-03f);
        p = fmaf(p, w, -4.17768164e-03f);
        p = fmaf(p, w, 2.46640727e-01f);
        p = fmaf(p, w, 1.50140941e+00f);
    } else {
        w = sqrtf(w) - 3.0f;
        p = -2.00214257e-04f;
        p = fmaf(p, w, 1.00950558e-04f);
        p = fmaf(p, w, 1.34934322e-03f);
        p = fmaf(p, w, -3.67342844e-03f);
        p = fmaf(p, w, 5.73950773e-03f);
        p = fmaf(p, w, -7.62246130e-03f);
        p = fmaf(p, w, 9.43887047e-03f);
        p = fmaf(p, w, 1.00167406e+00f);
        p = fmaf(p, w, 2.83297682e+00f);
    }
    return p * t;
}

struct Params {
    float muk[Kc], sk[Kc], rk[Kc], wk[Kc];
    float lb, ub;
};

// Per-thread prep (rescue kernel) -- byte-identical values to R13.
__device__ __forceinline__ void prep_params(int d, const float* __restrict__ logits,
                                            const float* __restrict__ mu,
                                            const float* __restrict__ logstd, Params& P)
{
    const float SQRT2F = 1.41421356237309515f;
    float lg[Kc];
#pragma unroll
    for (int k = 0; k < Kc; ++k) lg[k] = logits[k];
    float lmax = lg[0];
#pragma unroll
    for (int k = 1; k < Kc; ++k) lmax = fmaxf(lmax, lg[k]);
    float ew[Kc];
#pragma unroll
    for (int k = 0; k < Kc; ++k) ew[k] = cr_expf(__fsub_rn(lg[k], lmax));
    float wsum = ew[0];
#pragma unroll
    for (int k = 1; k < Kc; ++k) wsum = __fadd_rn(wsum, ew[k]);
#pragma unroll
    for (int k = 0; k < Kc; ++k) P.wk[k] = __fdiv_rn(ew[k], wsum);

    float ssum = 0.f;
#pragma unroll
    for (int k = 0; k < Kc; ++k) {
        P.muk[k] = mu[k * Dc + d];
        P.sk[k]  = cr_expf(logstd[k * Dc + d]);
        P.rk[k]  = (float)(1.0 / ((double)P.sk[k] * (double)SQRT2F));
        ssum     = __fadd_rn(ssum, P.sk[k]);
    }
    float m10 = __fmul_rn(10.0f, ssum);
    float lb = __fsub_rn(P.muk[0], m10);
    float ub = __fadd_rn(P.muk[0], m10);
#pragma unroll
    for (int k = 1; k < Kc; ++k) {
        lb = fminf(lb, __fsub_rn(P.muk[k], m10));
        ub = fmaxf(ub, __fadd_rn(P.muk[k], m10));
    }
    P.lb = lb; P.ub = ub;
}

// Bit-identical to R13's comparator evaluation (value channel).
__device__ __forceinline__ float Feval(float x, const Params& P) {
    float acc = 0.f;
#pragma unroll
    for (int k = 0; k < Kc; ++k) {
        float t   = __fmul_rn(__fsub_rn(x, P.muk[k]), P.rk[k]);
        float e   = erf_xla_f32(t);
        float cdf = __fmul_rn(0.5f, __fadd_rn(1.0f, e));
        acc = __fadd_rn(acc, __fmul_rn(cdf, P.wk[k]));
    }
    return acc;
}

// Bit-identical to R13's log-det epilogue.
__device__ __forceinline__ float logdet_exact(float x, const Params& P) {
    const float INV_SQRT_2PIF = 0.39894228040143267f;
    float p = 0.f;
#pragma unroll
    for (int k = 0; k < Kc; ++k) {
        float u   = __fdiv_rn(__fsub_rn(x, P.muk[k]), P.sk[k]);
        float q   = __fmul_rn(__fmul_rn(-0.5f, u), u);
        float pdf = __fmul_rn(cr_expf(q), __fdiv_rn(INV_SQRT_2PIF, P.sk[k]));
        p = __fadd_rn(p, __fmul_rn(pdf, P.wk[k]));
    }
    return -cr_logf(p);
}

// R13's exact trajectory (value-space bisection, reference update rule).
__device__ __forceinline__ void traj_solve(float zv, const Params& P, float& xo, float& nldo) {
    float x = 0.f, lb = P.lb, ub = P.ub;
    int stable = 0;
    for (int it = 0; it < 200; ++it) {
        float acc = Feval(x, P);
        bool gt = acc > zv;
        float nx = __fmul_rn(__fadd_rn(x, gt ? lb : ub), 0.5f);
        if (gt) ub = x; else lb = x;
        stable = (nx == x) ? (stable + 1) : 0;
        x = nx;
        if (__all(stable >= 2)) break;
    }
    xo = x;
    nldo = logdet_exact(x, P);
}

__global__ __launch_bounds__(256)
void k1_newton(const float* __restrict__ z_in, const float* __restrict__ logits,
               const float* __restrict__ mu, const float* __restrict__ logstd,
               float* __restrict__ out_x, float* __restrict__ out_nld,
               unsigned int* __restrict__ ws_count, unsigned int* __restrict__ ws_list,
               unsigned int cap)
{
    const float SQRT2F = 1.41421356237309515f;
    const float INV_SQRT_2PIF = 0.39894228040143267f;
    __shared__ float s_ew[Kc], s_wk[Kc];
    __shared__ float s_mu[Kc][Dc], s_s[Kc][Dc], s_r[Kc][Dc], s_c[Kc][Dc];
    __shared__ float s_lb[Dc], s_ub[Dc], s_m[Dc], s_sig[Dc];
    int tid = threadIdx.x;

    // ---- cooperative prep (CR transcendentals, once per block) ----
    if (tid < Kc) {
        float lmax = logits[0];
#pragma unroll
        for (int k = 1; k < Kc; ++k) lmax = fmaxf(lmax, logits[k]);
        s_ew[tid] = cr_expf(__fsub_rn(logits[tid], lmax));
    }
    if (tid < Kc * Dc) {
        int k = tid >> 4, d = tid & 15;
        s_mu[k][d] = mu[k * Dc + d];
        float s = cr_expf(logstd[k * Dc + d]);
        s_s[k][d] = s;
        s_r[k][d] = (float)(1.0 / ((double)s * (double)SQRT2F));
    }
    __syncthreads();
    if (tid < Kc) {
        float wsum = s_ew[0];
#pragma unroll
        for (int k = 1; k < Kc; ++k) wsum = __fadd_rn(wsum, s_ew[k]);
        s_wk[tid] = __fdiv_rn(s_ew[tid], wsum);
    }
    __syncthreads();
    if (tid < Dc) {
        float ssum = 0.f, m = 0.f;
#pragma unroll
        for (int k = 0; k < Kc; ++k) {
            ssum = __fadd_rn(ssum, s_s[k][tid]);
            m    = fmaf(s_wk[k], s_mu[k][tid], m);
        }
        float var = 0.f;
#pragma unroll
        for (int k = 0; k < Kc; ++k) {
            float dm = s_mu[k][tid] - m;
            var = fmaf(s_wk[k], fmaf(dm, dm, s_s[k][tid] * s_s[k][tid]), var);
        }
        s_m[tid]   = m;
        s_sig[tid] = sqrtf(var);
        float m10 = __fmul_rn(10.0f, ssum);
        float lb = __fsub_rn(s_mu[0][tid], m10);
        float ub = __fadd_rn(s_mu[0][tid], m10);
#pragma unroll
        for (int k = 1; k < Kc; ++k) {
            lb = fminf(lb, __fsub_rn(s_mu[k][tid], m10));
            ub = fmaxf(ub, __fadd_rn(s_mu[k][tid], m10));
        }
        s_lb[tid] = lb; s_ub[tid] = ub;
    }
    if (tid < Kc * Dc) {
        int k = tid >> 4, d = tid & 15;
        s_c[k][d] = s_wk[k] * INV_SQRT_2PIF / s_s[k][d];  // density coeff
    }
    __syncthreads();

    int i = blockIdx.x * blockDim.x + tid;   // Ntot % 256 == 0
    if (i >= Ntot) return;
    int d = i & (Dc - 1);
    float muk[Kc], rk[Kc], ck[Kc], wh[Kc];
#pragma unroll
    for (int k = 0; k < Kc; ++k) {
        muk[k] = s_mu[k][d]; rk[k] = s_r[k][d];
        ck[k]  = s_c[k][d];  wh[k] = 0.5f * s_wk[k];
    }
    float lb = s_lb[d], ub = s_ub[d];

    float zv = fminf(fmaxf(z_in[i], 0.f), 1.f);

    // ---- moment-matched Gaussian seed ----
    float tt = fminf(fmaxf(2.f * zv - 1.f, -0.999999f), 0.999999f);
    float x  = fmaf(s_sig[d] * SQRT2F, erfinv_f32(tt), s_m[d]);
    x = fminf(fmaxf(x, lb + 1e-3f), ub - 1e-3f);

    // ---- safeguarded Halley-Newton; flat lanes leave the exit condition ----
    float blo = lb, bhi = ub;
    float acc = 0.f, den = 0.f;
    bool conv = false, flat = false;
#pragma unroll 1
    for (int it = 0; it < 8; ++it) {
        acc = 0.5f; den = 0.f;
        float f2 = 0.f;                       // accumulates sum g*t*r (for F'')
#pragma unroll
        for (int k = 0; k < Kc; ++k) {
            float t  = (x - muk[k]) * rk[k];
            float tc = fminf(fmaxf(t, -4.f), 4.f);
            float y  = tc * tc;
            float a = fmaf(-2.72614225801306e-10f, y,  2.77068142495902e-08f);
            a = fmaf(a, y, -2.10102402082508e-06f);
            a = fmaf(a, y, -5.69250639462346e-05f);
            a = fmaf(a, y, -7.34990630326855e-04f);
            a = fmaf(a, y, -2.95459980854025e-03f);
            a = fmaf(a, y, -1.60960333262415e-02f);
            float b = fmaf(-1.45660718464996e-05f, y, -2.13374055278905e-04f);
            b = fmaf(b, y, -1.68282697438203e-03f);
            b = fmaf(b, y, -7.37332916720468e-03f);
            b = fmaf(b, y, -1.42647390514189e-02f);
            float e = (tc * a) * __builtin_amdgcn_rcpf(b);
            acc = fmaf(wh[k], e, acc);                 // F = 0.5 + sum wh*e
            float g = ck[k] * __expf(-t * t);          // density component
            den = den + g;
            f2  = fmaf(g, t * rk[k], f2);              // for F'' = -2*f2
        }
        float r = acc - zv;
        conv = conv || (fabsf(r) <= 1.5e-3f * den);
        // destined-for-rescue lanes (1-iter grace for transient valleys):
        flat = flat || ((den < 1e-3f) && (it >= 1));
        bool active = !(conv || flat);
        if (__all(!active)) break;
        if (active) {
            bool gt = r > 0.f;
            if (gt) bhi = x; else blo = x;
            float invd = __builtin_amdgcn_rcpf(den);
            float nstep = r * invd;                    // Newton step
            // Halley: step = nstep / (1 + r*f2/den^2); F'' = -2*f2
            float hden = fmaf(nstep * invd, f2, 1.0f);
            hden = fminf(fmaxf(hden, 0.5f), 2.0f);
            float xn = x - nstep * __builtin_amdgcn_rcpf(hden);
            if (!(xn > blo && xn < bhi)) xn = 0.5f * (blo + bhi);
            x = xn;
        }
    }

    // ---- acceptance: converged AND decent density at exit ----
    bool rescue = (!conv) || (den < 1e-3f);

    float xout = 0.f, nldout = 0.f;
    if (!rescue) {
        xout   = x;
        nldout = -__logf(den);                         // fast logdet (err ~1e-6)
    } else {
        unsigned int idx = atomicAdd(ws_count, 1u);
        if (idx < cap) {
            ws_list[idx] = (unsigned int)i;
        } else {
            Params P;                                  // no scratch room: inline
            prep_params(d, logits, mu, logstd, P);
            traj_solve(zv, P, xout, nldout);
        }
    }
    out_x[i]   = xout;
    out_nld[i] = nldout;
}

__global__ __launch_bounds__(256)
void k2_rescue(const float* __restrict__ z_in, const float* __restrict__ logits,
               const float* __restrict__ mu, const float* __restrict__ logstd,
               float* __restrict__ out_x, float* __restrict__ out_nld,
               const unsigned int* __restrict__ ws_count,
               const unsigned int* __restrict__ ws_list, unsigned int cap)
{
    unsigned int n = *ws_count;
    if (n > cap) n = cap;
    for (unsigned int j = blockIdx.x * blockDim.x + threadIdx.x; j < n;
         j += gridDim.x * blockDim.x) {
        int i = (int)ws_list[j];
        Params P;
        prep_params(i & (Dc - 1), logits, mu, logstd, P);
        float zv = fminf(fmaxf(z_in[i], 0.f), 1.f);
        float x, nld;
        traj_solve(zv, P, x, nld);
        out_x[i]   = x;
        out_nld[i] = nld;
    }
}

extern "C" void kernel_launch(void* const* d_in, const int* in_sizes, int n_in,
                              void* d_out, int out_size, void* d_ws, size_t ws_size,
                              hipStream_t stream) {
    const float* z      = (const float*)d_in[0];
    const float* logits = (const float*)d_in[1];
    const float* mu     = (const float*)d_in[2];
    const float* logstd = (const float*)d_in[3];
    float* out_x   = (float*)d_out;
    float* out_nld = (float*)d_out + Ntot;

    unsigned int* ws_count = (unsigned int*)d_ws;
    unsigned int* ws_list  = (unsigned int*)((char*)d_ws + 16);
    size_t cap_sz = (ws_size > 16) ? (ws_size - 16) / 4 : 0;
    unsigned int cap = (unsigned int)((cap_sz > (size_t)Ntot) ? (size_t)Ntot : cap_sz);

    hipMemsetAsync(d_ws, 0, 16, stream);
    int threads = 256;
    int blocks  = (Ntot + threads - 1) / threads;
    k1_newton<<<blocks, threads, 0, stream>>>(z, logits, mu, logstd, out_x, out_nld,
                                              ws_count, ws_list, cap);
    k2_rescue<<<1024, threads, 0, stream>>>(z, logits, mu, logstd, out_x, out_nld,
                                            ws_count, ws_list, cap);
}